// Round 5
// baseline (507.731 us; speedup 1.0000x reference)
//
#include <hip/hip_runtime.h>
#include <hip/hip_cooperative_groups.h>

namespace cg = cooperative_groups;

#define K_DIM 4096
#define N_DIM 8192   // rows of x
#define M_DIM 4096   // rows of weight

typedef int v4i __attribute__((ext_vector_type(4)));

// ---------------- fused amax + quantize (cooperative, one kernel) ----------
// Phase 1: every block computes max|.| over its contiguous x-span and w-span,
// atomicMax into scal. grid.sync(). Phase 2: re-read the same spans (L3-hot)
// and write int8. Removes one full 192 MB HBM read pass + one launch vs the
// two-kernel version, and makes the prelude a single visible dispatch.
__device__ __forceinline__ unsigned pack4(float4 v, float s) {
  int q0 = (int)fminf(fmaxf(rintf(v.x * s), -127.f), 127.f);
  int q1 = (int)fminf(fmaxf(rintf(v.y * s), -127.f), 127.f);
  int q2 = (int)fminf(fmaxf(rintf(v.z * s), -127.f), 127.f);
  int q3 = (int)fminf(fmaxf(rintf(v.w * s), -127.f), 127.f);
  return (unsigned)(q0 & 255) | ((unsigned)(q1 & 255) << 8) |
         ((unsigned)(q2 & 255) << 16) | ((unsigned)(q3 & 255) << 24);
}

__global__ __launch_bounds__(256, 4) void amaxquant_kernel(
    const float4* __restrict__ x, const float4* __restrict__ w,
    unsigned* __restrict__ qx, unsigned* __restrict__ qw,
    unsigned* __restrict__ scal) {
  // x: 8.39M float4 / 512 blocks = 16384/block (64/thread)
  // w: 4.19M float4 / 512 blocks =  8192/block (32/thread)
  const long xb = (long)blockIdx.x * 16384 + threadIdx.x;
  const long wb = (long)blockIdx.x * 8192 + threadIdx.x;
  float m0 = 0.f, m1 = 0.f;
#pragma unroll 4
  for (int k = 0; k < 64; ++k) {
    float4 v = x[xb + (long)k * 256];
    m0 = fmaxf(m0, fmaxf(fmaxf(fabsf(v.x), fabsf(v.y)),
                         fmaxf(fabsf(v.z), fabsf(v.w))));
  }
#pragma unroll 4
  for (int k = 0; k < 32; ++k) {
    float4 v = w[wb + (long)k * 256];
    m1 = fmaxf(m1, fmaxf(fmaxf(fabsf(v.x), fabsf(v.y)),
                         fmaxf(fabsf(v.z), fabsf(v.w))));
  }
#pragma unroll
  for (int off = 32; off > 0; off >>= 1) {
    m0 = fmaxf(m0, __shfl_down(m0, off));
    m1 = fmaxf(m1, __shfl_down(m1, off));
  }
  __shared__ float s0[4], s1[4];
  const int lane = threadIdx.x & 63, wv = threadIdx.x >> 6;
  if (lane == 0) { s0[wv] = m0; s1[wv] = m1; }
  __syncthreads();
  if (threadIdx.x == 0) {
    atomicMax(scal + 0, __float_as_uint(fmaxf(fmaxf(s0[0], s0[1]),
                                              fmaxf(s0[2], s0[3]))));
    atomicMax(scal + 1, __float_as_uint(fmaxf(fmaxf(s1[0], s1[1]),
                                              fmaxf(s1[2], s1[3]))));
  }
  cg::this_grid().sync();
  const float sx = 127.0f / __uint_as_float(scal[0]);
  const float sw = 127.0f / __uint_as_float(scal[1]);
#pragma unroll 4
  for (int k = 0; k < 64; ++k)
    qx[xb + (long)k * 256] = pack4(x[xb + (long)k * 256], sx);
#pragma unroll 4
  for (int k = 0; k < 32; ++k)
    qw[wb + (long)k * 256] = pack4(w[wb + (long)k * 256], sw);
}

// ---------------- int8 GEMM: out = qx (N,K) * qw^T (K,M), dequant + bias ----
__device__ __forceinline__ void gld_lds16(const void* g, void* l) {
  __builtin_amdgcn_global_load_lds(
      (const __attribute__((address_space(1))) void*)g,
      (__attribute__((address_space(3))) void*)l, 16, 0, 0);
}

// 256x256 tile, BK=64 bytes, 4 waves (2M x 2N), per-wave 128x128 output.
// LDS-balance rationale: LDS is CU-shared (~85-112 B/cy) vs MFMA per-CU
// (~6420 i8 ops/cy); per-wave reads (Wm+Wn)*BK bytes for 2*Wm*Wn*BK ops, so
// need h = 2WmWn/(Wm+Wn) >= ~75. 64x64 -> h=64 (LDS-bound, R4 regression
// confirmed); 128x64 -> h=85 (marginal, 45% util plateau); 128x128 -> h=128.
// Cost: 256 acc VGPRs -> 1 wave/SIMD; compiler's incremental lgkm waits let
// each wave's 64-MFMA burst start after its first ~9 of 16 ds_reads, so the
// CU read backlog overlaps the MFMA chain.
// Ring-4 LDS (4 x 32 KiB), one s_barrier + one counted vmcnt per K-tile:
// STAGE(T+3) overwrites the slot last read at tile T-1, whose reads all
// waves completed before crossing the tile-T barrier.
// LDS fold-XOR layout (measured 0-conflict): logical [256 rows][64B] stored
// as [128 phys rows][8 chunks x 16B]; phys row r holds logical rows r,r+128;
// stored chunk = ((half<<2)|kq) ^ (r&7).
__global__ __launch_bounds__(256, 1) void gemm_i8(
    const signed char* __restrict__ A,   // qx  [N_DIM][K_DIM]
    const signed char* __restrict__ B,   // qw  [M_DIM][K_DIM]
    const float* __restrict__ bias,      // [M_DIM]
    float* __restrict__ out,             // [N_DIM][M_DIM]
    const unsigned* __restrict__ scal)   // [0]=amax_x bits [1]=amax_w bits
{
  __shared__ signed char lds[4][2][128 * 128];  // [slot][A/B][16 KiB] = 128 KiB

  const int tid = threadIdx.x;   // 256
  const int lane = tid & 63;
  const int w = tid >> 6;        // wave 0..3
  const int wm = w >> 1;         // 0..1 (128-row half)
  const int wn = w & 1;          // 0..1 (128-col half)

  // XCD-aware bijective swizzle: 512 wgs, 8 XCDs, 8x8 tile blob per XCD
  const int bid = blockIdx.x;
  const int xcd = bid & 7, idx = bid >> 3;     // 512 % 8 == 0: bijective
  const int bx = (xcd & 3) * 8 + (idx & 7);    // 0..31 (N tiles)
  const int by = (xcd >> 2) * 8 + (idx >> 3);  // 0..15 (M tiles)
  const long r0 = (long)bx * 256;
  const long c0 = (long)by * 256;

  // staging: pass p (0..3) covers phys rows 32p..32p+31; thread t -> phys row
  // 32p+(t>>3), chunk t&7 (linear dest). Inverse swizzle on the source:
  // u=(t&7)^((t>>3)&7); logical row = (u>>2)*128 + 32p + (t>>3); kcol=(u&3)*16.
  const int u = (tid & 7) ^ ((tid >> 3) & 7);
  const long sR = (long)(u >> 2) * 128 + (tid >> 3);
  const int scol = (u & 3) * 16;
  const signed char* gA = A + (r0 + sR) * K_DIM + scol;
  const signed char* gB = B + (c0 + sR) * K_DIM + scol;
  const int ldst = tid * 16;

  v4i acc[8][8];
#pragma unroll
  for (int i = 0; i < 8; ++i)
#pragma unroll
    for (int j = 0; j < 8; ++j) acc[i][j] = (v4i){0, 0, 0, 0};

  const int fr = lane & 15;   // fragment row (m or n)
  const int fq = lane >> 4;   // 16B k-chunk (0..3)
  const int sk = fr & 7;      // swizzle key

  const int aoff = fr * 128 + (((wm << 2) | fq) ^ sk) * 16;  // + mi*2048
  const int boff = fr * 128 + (((wn << 2) | fq) ^ sk) * 16;  // + nf*2048

  auto STAGE = [&](int T) {
    signed char* la = &lds[T & 3][0][0];
    signed char* lb = &lds[T & 3][1][0];
    const long ko = (long)T * 64;
#pragma unroll
    for (int p = 0; p < 4; ++p) {
      gld_lds16(gA + (long)p * 32 * K_DIM + ko, la + p * 4096 + ldst);
      gld_lds16(gB + (long)p * 32 * K_DIM + ko, lb + p * 4096 + ldst);
    }
  };

  auto TILE = [&](int T, bool stg, int guard) {
    // guard: my 8 loads for tile T (oldest) are done; barrier then implies
    // ALL waves' tile-T loads landed and all waves finished tile T-1 reads.
    if (guard == 16) asm volatile("s_waitcnt vmcnt(16)" ::: "memory");
    else if (guard == 8) asm volatile("s_waitcnt vmcnt(8)" ::: "memory");
    else asm volatile("s_waitcnt vmcnt(0)" ::: "memory");
    __builtin_amdgcn_s_barrier();
    if (stg) STAGE(T + 3);  // slot (T+3)&3 == (T-1)&3, free since barrier T
    const signed char* la = &lds[T & 3][0][0];
    const signed char* lb = &lds[T & 3][1][0];
    v4i bv[8], av[8];
#pragma unroll
    for (int nf = 0; nf < 8; ++nf)
      bv[nf] = *(const v4i*)(lb + boff + nf * 2048);
#pragma unroll
    for (int mi = 0; mi < 8; ++mi)
      av[mi] = *(const v4i*)(la + aoff + mi * 2048);
    __builtin_amdgcn_s_setprio(1);
#pragma unroll
    for (int mi = 0; mi < 8; ++mi)
#pragma unroll
      for (int nf = 0; nf < 8; ++nf)
        acc[mi][nf] = __builtin_amdgcn_mfma_i32_16x16x64_i8(av[mi], bv[nf],
                                                            acc[mi][nf], 0, 0, 0);
    __builtin_amdgcn_s_setprio(0);
  };

  const int NT = K_DIM / 64;  // 64 K-tiles
  STAGE(0);
  STAGE(1);
  STAGE(2);
#pragma unroll 1
  for (int T = 0; T < NT - 3; ++T) TILE(T, true, 16);  // stages 3..NT-1
  TILE(NT - 3, false, 16);
  TILE(NT - 2, false, 8);
  TILE(NT - 1, false, 0);

  const float dq =
      (__uint_as_float(scal[0]) * __uint_as_float(scal[1])) / 16129.0f;
  float bs[8];
#pragma unroll
  for (int nf = 0; nf < 8; ++nf) bs[nf] = bias[c0 + wn * 128 + nf * 16 + fr];

#pragma unroll
  for (int mi = 0; mi < 8; ++mi) {
    const long rbase = r0 + wm * 128 + mi * 16 + fq * 4;  // C/D row=(lane>>4)*4+t
#pragma unroll
    for (int nf = 0; nf < 8; ++nf) {
      const long c = c0 + wn * 128 + nf * 16 + fr;        // C/D col=lane&15
#pragma unroll
      for (int t = 0; t < 4; ++t) {
        out[(rbase + t) * (long)M_DIM + c] = (float)acc[mi][nf][t] * dq + bs[nf];
      }
    }
  }
}

extern "C" void kernel_launch(void* const* d_in, const int* in_sizes, int n_in,
                              void* d_out, int out_size, void* d_ws, size_t ws_size,
                              hipStream_t stream) {
  const float* x = (const float*)d_in[0];      // [8192,4096]
  const float* wt = (const float*)d_in[1];     // [4096,4096]
  const float* bias = (const float*)d_in[2];   // [4096]
  float* out = (float*)d_out;

  unsigned* scal = (unsigned*)d_ws;                       // 2 scalars
  signed char* qx = (signed char*)d_ws + 256;             // 32 MiB
  signed char* qw = qx + (long)N_DIM * K_DIM;             // 16 MiB

  hipMemsetAsync(d_ws, 0, 16, stream);  // zero amax slots (ws poisoned 0xAA)

  const float4* x4 = (const float4*)x;
  const float4* w4 = (const float4*)wt;
  unsigned* qxu = (unsigned*)qx;
  unsigned* qwu = (unsigned*)qw;
  void* args[] = {(void*)&x4, (void*)&w4, (void*)&qxu, (void*)&qwu,
                  (void*)&scal};
  hipLaunchCooperativeKernel((const void*)amaxquant_kernel, dim3(512),
                             dim3(256), args, 0, stream);

  gemm_i8<<<512, 256, 0, stream>>>(qx, qw, bias, out, scal);
}